// Round 1
// baseline (249.233 us; speedup 1.0000x reference)
//
#include <hip/hip_runtime.h>

// VecInt: scaling-and-squaring integration of stationary velocity field.
// flow: (2,128,128,128,3) fp32. vec = flow/128; 7x: vec += trilinear(vec, grid+vec).
// One thread per voxel per step; ping-pong d_out <-> d_ws so step 7 lands in d_out.

#define DIM 128
#define VOLN (DIM * DIM * DIM)   // voxels per batch
#define NBATCH 2
#define TOTVOX (NBATCH * VOLN)

__global__ __launch_bounds__(256) void vecint_step(const float* __restrict__ vin,
                                                   float* __restrict__ vout,
                                                   float scale) {
    int tid = blockIdx.x * blockDim.x + threadIdx.x;
    // decompose: w fastest, then h, d, b  (DIM=128 = 2^7)
    int w = tid & 127;
    int h = (tid >> 7) & 127;
    int d = (tid >> 14) & 127;
    int b = tid >> 21;

    const float* __restrict__ vb = vin + (size_t)b * (VOLN * 3);
    size_t base = (size_t)tid * 3;

    // own velocity (scale folded in: step 1 reads raw flow with scale=1/128)
    float v0 = vin[base + 0] * scale;
    float v1 = vin[base + 1] * scale;
    float v2 = vin[base + 2] * scale;

    // sample location = identity grid + vec, clamped to [0, 127]
    float ld = fminf(fmaxf((float)d + v0, 0.0f), 127.0f);
    float lh = fminf(fmaxf((float)h + v1, 0.0f), 127.0f);
    float lw = fminf(fmaxf((float)w + v2, 0.0f), 127.0f);

    float fd0 = floorf(ld), fh0 = floorf(lh), fw0 = floorf(lw);
    int id0 = (int)fd0, ih0 = (int)fh0, iw0 = (int)fw0;
    float td = ld - fd0, th = lh - fh0, tw = lw - fw0;
    int id1 = min(id0 + 1, 127);
    int ih1 = min(ih0 + 1, 127);
    int iw1 = min(iw0 + 1, 127);

    float wd0 = 1.0f - td, wd1 = td;
    float wh0 = 1.0f - th, wh1 = th;
    float ww0 = 1.0f - tw, ww1 = tw;

    // accumulate raw (unscaled) trilinear sample; scale applied once at the end
    float a0 = 0.0f, a1 = 0.0f, a2 = 0.0f;

#define CORNER(IDD, IHH, IWW, WGT)                                  \
    {                                                               \
        int flat = (((IDD) * DIM + (IHH)) * DIM + (IWW)) * 3;       \
        float g = (WGT);                                            \
        a0 = fmaf(g, vb[flat + 0], a0);                             \
        a1 = fmaf(g, vb[flat + 1], a1);                             \
        a2 = fmaf(g, vb[flat + 2], a2);                             \
    }

    CORNER(id0, ih0, iw0, wd0 * wh0 * ww0)
    CORNER(id0, ih0, iw1, wd0 * wh0 * ww1)
    CORNER(id0, ih1, iw0, wd0 * wh1 * ww0)
    CORNER(id0, ih1, iw1, wd0 * wh1 * ww1)
    CORNER(id1, ih0, iw0, wd1 * wh0 * ww0)
    CORNER(id1, ih0, iw1, wd1 * wh0 * ww1)
    CORNER(id1, ih1, iw0, wd1 * wh1 * ww0)
    CORNER(id1, ih1, iw1, wd1 * wh1 * ww1)
#undef CORNER

    vout[base + 0] = v0 + scale * a0;
    vout[base + 1] = v1 + scale * a1;
    vout[base + 2] = v2 + scale * a2;
}

extern "C" void kernel_launch(void* const* d_in, const int* in_sizes, int n_in,
                              void* d_out, int out_size, void* d_ws, size_t ws_size,
                              hipStream_t stream) {
    const float* flow = (const float*)d_in[0];
    float* out = (float*)d_out;
    float* ws = (float*)d_ws;   // needs 2*128^3*3*4 = 50.3 MB

    const int threads = 256;
    const int blocks = TOTVOX / threads;  // 16384
    const float s = 1.0f / 128.0f;        // 1 / 2^INT_STEPS

    // 7 steps, ping-pong so the final result lands in d_out
    vecint_step<<<blocks, threads, 0, stream>>>(flow, out, s);    // 1
    vecint_step<<<blocks, threads, 0, stream>>>(out,  ws,  1.f);  // 2
    vecint_step<<<blocks, threads, 0, stream>>>(ws,   out, 1.f);  // 3
    vecint_step<<<blocks, threads, 0, stream>>>(out,  ws,  1.f);  // 4
    vecint_step<<<blocks, threads, 0, stream>>>(ws,   out, 1.f);  // 5
    vecint_step<<<blocks, threads, 0, stream>>>(out,  ws,  1.f);  // 6
    vecint_step<<<blocks, threads, 0, stream>>>(ws,   out, 1.f);  // 7
}